// Round 6
// baseline (240.309 us; speedup 1.0000x reference)
//
#include <hip/hip_runtime.h>

// InternalInteraction: out[b,j,d] = sum_i [ relu((x_i*x_j)@W1^T + b1) @ W2^T + b2 ]
// Factored: hsum[b,j,h] = sum_i relu((x_i*x_j)@W1^T + b1); out = hsum@W2^T + 16*b2.
// B=2048, A=16, D=128, H=512. Storage fp32; MFMA in bf16.
//
// Round-9 structure (vs round-8):
//  - POST-MORTEM r8: symmetry cut landed (95->87us, no spill). Pipes now:
//    LDS ~40us (dominant), VALU ~21, MFMA ~17. Largest LDS item: the 112
//    ds_bpermute/wave (~672 cyc/wave ~ 18us/dispatch) doing the rotated add.
//  - DPP-HORNER ROTATION: rotated sum = sum_{dlt=1..7} R^dlt v_dlt with
//    R = rotate-by-1 in the 16-lane col group. Horner: run dlt 8->0 with
//    S = v_dlt + ror1(S) for dlt in [1,7], then hsum += ror1(S) at the end.
//    ror1 = DPP row_ror:1 (VALU, zero LDS) -- rotate amount is now the
//    CONSTANT 1, so no runtime lane index, no bpermute, loop stays unroll-1
//    (r7's spill trap avoided). 112 LDS bpermutes -> 112 mov_dpp (VALU).
//    Same relu'd values summed; only f32 add order changes.
//  - Everything else identical to r8: swapped-operand GEMM1 (C rows=h,
//    cols=j), 9 shift tiles, unroll-1, 512 thr / 8 waves / 64 h per wave,
//    f32 xs staging, hs aliasing dead ps.

#define BATCH 2048
#define AA 16
#define DD 128
#define HH 512

typedef __bf16 bf16;
typedef bf16  bf16x4 __attribute__((ext_vector_type(4)));
typedef bf16  bf16x8 __attribute__((ext_vector_type(8)));
typedef float f32x4  __attribute__((ext_vector_type(4)));

__device__ inline f32x4 splat4(float v) { f32x4 r = {v, v, v, v}; return r; }

// rotate within each 16-lane row: lane j takes lane (j-1)&15 (DPP row_ror:1)
__device__ inline float ror1_f32(float v) {
    return __int_as_float(__builtin_amdgcn_mov_dpp(
        __float_as_int(v), 0x121, 0xF, 0xF, false));
}

// ---- prologue: fp32 -> bf16 weight conversion into d_ws ----
// ws layout: [0, 65536)  = W1b (512x128 row-major bf16)
//            [65536, ..) = W2b (128x512 row-major bf16)
__global__ __launch_bounds__(256, 1)
void convert_weights(const float* __restrict__ W1,
                     const float* __restrict__ W2,
                     bf16* __restrict__ wsb)
{
    int t = blockIdx.x * 256 + threadIdx.x;      // 0..32767, 4 elems each
    f32x4 v = (t < 16384) ? *(const f32x4*)(W1 + 4 * t)
                          : *(const f32x4*)(W2 + 4 * (t - 16384));
    bf16x4 o;
    o[0] = (bf16)v[0]; o[1] = (bf16)v[1]; o[2] = (bf16)v[2]; o[3] = (bf16)v[3];
    *(bf16x4*)(wsb + 4 * t) = o;
}

// One block per batch. 512 threads = 8 waves; wave w owns H cols [w*64, w*64+64).
__global__ __launch_bounds__(512, 4)
void interact_kernel(const float* __restrict__ x,    // [B, A, D] fp32
                     const bf16*  __restrict__ W1b,  // [H, D] bf16 (from ws)
                     const float* __restrict__ b1,   // [H]
                     const bf16*  __restrict__ W2b,  // [D, H] bf16 (from ws)
                     const float* __restrict__ b2,   // [D]
                     float* __restrict__ out)        // [B, A, D] fp32
{
    // xs: x_b in f32, row stride 136 (544 B)
    __shared__ float xs[16][136];                               // 8704 B
    // ps: 9 shift-tiles [dlt][j][136] bf16; tile dlt row j = x_{(j+dlt)&15}*x_j.
    //     row stride 272 B -> frag b128 reads uniform over 8 bank-slots.
    // hs: GEMM2 staging [16][520] bf16 (16640 B) -- ALIASES ps (dead by then).
    __shared__ __align__(16) unsigned char smem_raw[9 * 16 * 136 * 2];  // 39168 B
    bf16 (*ps)[16][136] = reinterpret_cast<bf16(*)[16][136]>(smem_raw);
    bf16 (*hs)[520]     = reinterpret_cast<bf16(*)[520]>(smem_raw);

    const int b    = blockIdx.x;
    const int tid  = threadIdx.x;
    const int wave = tid >> 6;    // 0..7
    const int lane = tid & 63;
    const int quad = lane >> 4;   // 0..3
    const int col  = lane & 15;   // 0..15

    // build-phase coordinates: thread owns (jrow, dq..dq+4)
    const int jrow = tid >> 5;          // 0..15
    const int dq   = (tid & 31) * 4;    // 0..124

    // ---- stage x_b into LDS (f32); keep own 4-float slice in regs ----
    f32x4 xj;
    {
        const float* src = x + (size_t)b * (AA * DD) + jrow * DD + dq;
        xj = *(const f32x4*)src;
        *(f32x4*)(&xs[jrow][dq]) = xj;
    }

    // ---- W1 fragments, register-resident (4n x 4kk x 16B = 64 regs) ----
    // Used as MFMA arg0 (A-operand): lane holds W1b[h = n*16+col][k-slice].
    bf16x8 w1f[4][4];
    f32x4  bias4[4];   // C-seed: b1[h0 + quad*4 + r] per reg r (C rows = h)
#pragma unroll
    for (int n = 0; n < 4; ++n) {
        int h    = wave * 64 + n * 16 + col;
        bias4[n] = *(const f32x4*)(b1 + wave * 64 + n * 16 + quad * 4);
#pragma unroll
        for (int kk = 0; kk < 4; ++kk)
            w1f[n][kk] = *(const bf16x8*)(W1b + h * DD + kk * 32 + quad * 8);
    }

    f32x4 hsum[4];   // aligned accumulator
    f32x4 srot[4];   // Horner accumulator for the rotated sum
#pragma unroll
    for (int n = 0; n < 4; ++n) { hsum[n] = splat4(0.f); srot[n] = splat4(0.f); }

    __syncthreads();   // xs complete

    // ---- build 9 shift tiles: ps[dlt][j][d] = bf16(x_{(j+dlt)&15}[d]*x_j[d]) ----
#pragma unroll
    for (int dlt = 0; dlt < 9; ++dlt) {
        f32x4 xi = *(f32x4*)(&xs[(jrow + dlt) & 15][dq]);
        bf16x4 pr;
#pragma unroll
        for (int e = 0; e < 4; ++e) pr[e] = (bf16)(xj[e] * xi[e]);
        *(bf16x4*)(&ps[dlt][jrow][dq]) = pr;
    }
    __syncthreads();   // all tiles ready; no barriers until GEMM2 staging

    // ---- GEMM1 over 9 shift tiles (SWAPPED operands: C rows=h, cols=j) ----
    // v_dlt = relu(W1 @ pair_dlt + b1); lane(q,c) holds v[h=base+n*16+q*4+r][j=c].
    // hsum[j]  = sum_{dlt=0..8} v_dlt[j]                     (aligned adds)
    // rotated  = sum_{dlt=1..7} v_dlt[(j-dlt)&15]            (tiles 16-dlt)
    // Horner over DESCENDING dlt: srot = v_dlt + ror1(srot) for dlt=7..1;
    // then rotated = ror1(srot). ror1 is DPP row_ror:1 -- pure VALU.
#pragma unroll 1
    for (int dlt = 8; dlt >= 0; --dlt) {
        bf16x8 af[4];
#pragma unroll
        for (int kk = 0; kk < 4; ++kk)
            af[kk] = *(bf16x8*)(&ps[dlt][col][kk * 32 + quad * 8]);

        f32x4 v[4];
#pragma unroll
        for (int n = 0; n < 4; ++n)
            v[n] = __builtin_amdgcn_mfma_f32_16x16x32_bf16(
                w1f[n][0], af[0], bias4[n], 0, 0, 0);
#pragma unroll
        for (int kk = 1; kk < 4; ++kk)
#pragma unroll
            for (int n = 0; n < 4; ++n)
                v[n] = __builtin_amdgcn_mfma_f32_16x16x32_bf16(
                    w1f[n][kk], af[kk], v[n], 0, 0, 0);

        // relu + aligned add
#pragma unroll
        for (int n = 0; n < 4; ++n)
#pragma unroll
            for (int r = 0; r < 4; ++r) {
                v[n][r] = fmaxf(v[n][r], 0.f);
                hsum[n][r] += v[n][r];
            }

        // Horner step for the rotated sum (uniform branch, unroll-1 loop)
        if (dlt >= 1 && dlt <= 7) {
#pragma unroll
            for (int n = 0; n < 4; ++n)
#pragma unroll
                for (int r = 0; r < 4; ++r)
                    srot[n][r] = v[n][r] + ror1_f32(srot[n][r]);
        }
    }

    // close the Horner chain: hsum += R(srot)
#pragma unroll
    for (int n = 0; n < 4; ++n)
#pragma unroll
        for (int r = 0; r < 4; ++r)
            hsum[n][r] += ror1_f32(srot[n][r]);

    __syncthreads();   // all ps reads done before hs overwrites the region

    // ---- hsum -> LDS (bf16) for GEMM2 A-operand re-layout ----
    // Transposed C layout: lane(q,c) holds hsum[j=c][h = w*64+n*16+q*4+r]
    // -> contiguous in h: one bf16x4 store per n.
#pragma unroll
    for (int n = 0; n < 4; ++n) {
        bf16x4 o;
#pragma unroll
        for (int r = 0; r < 4; ++r) o[r] = (bf16)hsum[n][r];
        *(bf16x4*)(&hs[col][wave * 64 + n * 16 + quad * 4]) = o;
    }

    __syncthreads();

    // ---- GEMM2: out[j,d] = hsum[j,:] @ W2^T + 16*b2 ----
    // M=16 (j), N=16 per wave (d = wave*16 + col), K=512 (h). W2b is [D,H].
    const int d = wave * 16 + col;
    f32x4 acc2 = splat4(16.f * b2[d]);

#pragma unroll
    for (int ks = 0; ks < 16; ++ks) {
        int h0 = ks * 32 + quad * 8;
        bf16x8 a2 = *(bf16x8*)(&hs[col][h0]);
        bf16x8 bw = *(const bf16x8*)(W2b + d * HH + h0);
        acc2 = __builtin_amdgcn_mfma_f32_16x16x32_bf16(a2, bw, acc2, 0, 0, 0);
    }

#pragma unroll
    for (int r = 0; r < 4; ++r) {
        int j = quad * 4 + r;
        out[(size_t)b * (AA * DD) + j * DD + d] = acc2[r];
    }
}

extern "C" void kernel_launch(void* const* d_in, const int* in_sizes, int n_in,
                              void* d_out, int out_size, void* d_ws, size_t ws_size,
                              hipStream_t stream)
{
    const float* x  = (const float*)d_in[0];  // [2048,16,128]
    const float* W1 = (const float*)d_in[1];  // [512,128]
    const float* b1 = (const float*)d_in[2];  // [512]
    const float* W2 = (const float*)d_in[3];  // [128,512]
    const float* b2 = (const float*)d_in[4];  // [128]
    float* out = (float*)d_out;

    bf16* wsb = (bf16*)d_ws;                  // 256 KB used
    convert_weights<<<128, 256, 0, stream>>>(W1, W2, wsb);

    const bf16* W1b = wsb;
    const bf16* W2b = wsb + (size_t)HH * DD;
    interact_kernel<<<BATCH, 512, 0, stream>>>(x, W1b, b1, W2b, b2, out);
}

// Round 7
// 165.524 us; speedup vs baseline: 1.4518x; 1.4518x over previous
//
#include <hip/hip_runtime.h>

// InternalInteraction: out[b,j,d] = sum_i [ relu((x_i*x_j)@W1^T + b1) @ W2^T + b2 ]
// Factored: hsum[b,j,h] = sum_i relu((x_i*x_j)@W1^T + b1); out = hsum@W2^T + 16*b2.
// B=2048, A=16, D=128, H=512. Storage fp32; MFMA in bf16.
//
// Round-10 structure (vs round-9):
//  - POST-MORTEM r9: DPP-Horner was correct but SPILLED: under
//    __launch_bounds__(512,4) the 128-reg unified budget splits into
//    ~64 arch-VGPR + ~64 AGPR; srot (+16 DPP-bound regs, must be VGPR)
//    overflowed the VGPR partition -> 95 MB scratch, 87->180us.
//  - FIX (one variable): __launch_bounds__(512, 2) -> 256-reg budget.
//    Costs occupancy (1 block/CU, 8 waves) -- r5 proved this kernel is
//    occupancy-insensitive (2x waves = 0 delta), so registers are the
//    cheaper currency. Everything else is byte-identical to r9.
//  - DPP-HORNER ROTATION (kept): rotated sum = sum_{dlt=1..7} R^dlt v_dlt,
//    computed with constant rotate-by-1 (DPP row_ror:1, pure VALU):
//    srot = v_dlt + ror1(srot) for dlt=7..1, then hsum += ror1(srot).
//    Replaces 112 ds_bpermute/wave (LDS pipe, ~18us/dispatch) with
//    112 mov_dpp (VALU pipe). Same relu'd values; only f32 add order.
//  - Symmetry cut (r8): 9 shift tiles, swapped-operand GEMM1 (C rows=h,
//    cols=j), unroll-1 loop, 64 h-cols/wave, hs aliasing dead ps.

#define BATCH 2048
#define AA 16
#define DD 128
#define HH 512

typedef __bf16 bf16;
typedef bf16  bf16x4 __attribute__((ext_vector_type(4)));
typedef bf16  bf16x8 __attribute__((ext_vector_type(8)));
typedef float f32x4  __attribute__((ext_vector_type(4)));

__device__ inline f32x4 splat4(float v) { f32x4 r = {v, v, v, v}; return r; }

// rotate within each 16-lane row: lane j takes lane (j-1)&15 (DPP row_ror:1)
__device__ inline float ror1_f32(float v) {
    return __int_as_float(__builtin_amdgcn_mov_dpp(
        __float_as_int(v), 0x121, 0xF, 0xF, false));
}

// ---- prologue: fp32 -> bf16 weight conversion into d_ws ----
// ws layout: [0, 65536)  = W1b (512x128 row-major bf16)
//            [65536, ..) = W2b (128x512 row-major bf16)
__global__ __launch_bounds__(256, 1)
void convert_weights(const float* __restrict__ W1,
                     const float* __restrict__ W2,
                     bf16* __restrict__ wsb)
{
    int t = blockIdx.x * 256 + threadIdx.x;      // 0..32767, 4 elems each
    f32x4 v = (t < 16384) ? *(const f32x4*)(W1 + 4 * t)
                          : *(const f32x4*)(W2 + 4 * (t - 16384));
    bf16x4 o;
    o[0] = (bf16)v[0]; o[1] = (bf16)v[1]; o[2] = (bf16)v[2]; o[3] = (bf16)v[3];
    *(bf16x4*)(wsb + 4 * t) = o;
}

// One block per batch. 512 threads = 8 waves; wave w owns H cols [w*64, w*64+64).
__global__ __launch_bounds__(512, 2)
void interact_kernel(const float* __restrict__ x,    // [B, A, D] fp32
                     const bf16*  __restrict__ W1b,  // [H, D] bf16 (from ws)
                     const float* __restrict__ b1,   // [H]
                     const bf16*  __restrict__ W2b,  // [D, H] bf16 (from ws)
                     const float* __restrict__ b2,   // [D]
                     float* __restrict__ out)        // [B, A, D] fp32
{
    // xs: x_b in f32, row stride 136 (544 B)
    __shared__ float xs[16][136];                               // 8704 B
    // ps: 9 shift-tiles [dlt][j][136] bf16; tile dlt row j = x_{(j+dlt)&15}*x_j.
    //     row stride 272 B -> frag b128 reads uniform over 8 bank-slots.
    // hs: GEMM2 staging [16][520] bf16 (16640 B) -- ALIASES ps (dead by then).
    __shared__ __align__(16) unsigned char smem_raw[9 * 16 * 136 * 2];  // 39168 B
    bf16 (*ps)[16][136] = reinterpret_cast<bf16(*)[16][136]>(smem_raw);
    bf16 (*hs)[520]     = reinterpret_cast<bf16(*)[520]>(smem_raw);

    const int b    = blockIdx.x;
    const int tid  = threadIdx.x;
    const int wave = tid >> 6;    // 0..7
    const int lane = tid & 63;
    const int quad = lane >> 4;   // 0..3
    const int col  = lane & 15;   // 0..15

    // build-phase coordinates: thread owns (jrow, dq..dq+4)
    const int jrow = tid >> 5;          // 0..15
    const int dq   = (tid & 31) * 4;    // 0..124

    // ---- stage x_b into LDS (f32); keep own 4-float slice in regs ----
    f32x4 xj;
    {
        const float* src = x + (size_t)b * (AA * DD) + jrow * DD + dq;
        xj = *(const f32x4*)src;
        *(f32x4*)(&xs[jrow][dq]) = xj;
    }

    // ---- W1 fragments, register-resident (4n x 4kk x 16B = 64 regs) ----
    // Used as MFMA arg0 (A-operand): lane holds W1b[h = n*16+col][k-slice].
    bf16x8 w1f[4][4];
    f32x4  bias4[4];   // C-seed: b1[h0 + quad*4 + r] per reg r (C rows = h)
#pragma unroll
    for (int n = 0; n < 4; ++n) {
        int h    = wave * 64 + n * 16 + col;
        bias4[n] = *(const f32x4*)(b1 + wave * 64 + n * 16 + quad * 4);
#pragma unroll
        for (int kk = 0; kk < 4; ++kk)
            w1f[n][kk] = *(const bf16x8*)(W1b + h * DD + kk * 32 + quad * 8);
    }

    f32x4 hsum[4];   // aligned accumulator
    f32x4 srot[4];   // Horner accumulator for the rotated sum
#pragma unroll
    for (int n = 0; n < 4; ++n) { hsum[n] = splat4(0.f); srot[n] = splat4(0.f); }

    __syncthreads();   // xs complete

    // ---- build 9 shift tiles: ps[dlt][j][d] = bf16(x_{(j+dlt)&15}[d]*x_j[d]) ----
#pragma unroll
    for (int dlt = 0; dlt < 9; ++dlt) {
        f32x4 xi = *(f32x4*)(&xs[(jrow + dlt) & 15][dq]);
        bf16x4 pr;
#pragma unroll
        for (int e = 0; e < 4; ++e) pr[e] = (bf16)(xj[e] * xi[e]);
        *(bf16x4*)(&ps[dlt][jrow][dq]) = pr;
    }
    __syncthreads();   // all tiles ready; no barriers until GEMM2 staging

    // ---- GEMM1 over 9 shift tiles (SWAPPED operands: C rows=h, cols=j) ----
    // v_dlt = relu(W1 @ pair_dlt + b1); lane(q,c) holds v[h=base+n*16+q*4+r][j=c].
    // hsum[j]  = sum_{dlt=0..8} v_dlt[j]                     (aligned adds)
    // rotated  = sum_{dlt=1..7} v_dlt[(j-dlt)&15]            (tiles 16-dlt)
    // Horner over DESCENDING dlt: srot = v_dlt + ror1(srot) for dlt=7..1;
    // then rotated = ror1(srot). ror1 is DPP row_ror:1 -- pure VALU.
#pragma unroll 1
    for (int dlt = 8; dlt >= 0; --dlt) {
        bf16x8 af[4];
#pragma unroll
        for (int kk = 0; kk < 4; ++kk)
            af[kk] = *(bf16x8*)(&ps[dlt][col][kk * 32 + quad * 8]);

        f32x4 v[4];
#pragma unroll
        for (int n = 0; n < 4; ++n)
            v[n] = __builtin_amdgcn_mfma_f32_16x16x32_bf16(
                w1f[n][0], af[0], bias4[n], 0, 0, 0);
#pragma unroll
        for (int kk = 1; kk < 4; ++kk)
#pragma unroll
            for (int n = 0; n < 4; ++n)
                v[n] = __builtin_amdgcn_mfma_f32_16x16x32_bf16(
                    w1f[n][kk], af[kk], v[n], 0, 0, 0);

        // relu + aligned add
#pragma unroll
        for (int n = 0; n < 4; ++n)
#pragma unroll
            for (int r = 0; r < 4; ++r) {
                v[n][r] = fmaxf(v[n][r], 0.f);
                hsum[n][r] += v[n][r];
            }

        // Horner step for the rotated sum (uniform branch, unroll-1 loop)
        if (dlt >= 1 && dlt <= 7) {
#pragma unroll
            for (int n = 0; n < 4; ++n)
#pragma unroll
                for (int r = 0; r < 4; ++r)
                    srot[n][r] = v[n][r] + ror1_f32(srot[n][r]);
        }
    }

    // close the Horner chain: hsum += R(srot)
#pragma unroll
    for (int n = 0; n < 4; ++n)
#pragma unroll
        for (int r = 0; r < 4; ++r)
            hsum[n][r] += ror1_f32(srot[n][r]);

    __syncthreads();   // all ps reads done before hs overwrites the region

    // ---- hsum -> LDS (bf16) for GEMM2 A-operand re-layout ----
    // Transposed C layout: lane(q,c) holds hsum[j=c][h = w*64+n*16+q*4+r]
    // -> contiguous in h: one bf16x4 store per n.
#pragma unroll
    for (int n = 0; n < 4; ++n) {
        bf16x4 o;
#pragma unroll
        for (int r = 0; r < 4; ++r) o[r] = (bf16)hsum[n][r];
        *(bf16x4*)(&hs[col][wave * 64 + n * 16 + quad * 4]) = o;
    }

    __syncthreads();

    // ---- GEMM2: out[j,d] = hsum[j,:] @ W2^T + 16*b2 ----
    // M=16 (j), N=16 per wave (d = wave*16 + col), K=512 (h). W2b is [D,H].
    const int d = wave * 16 + col;
    f32x4 acc2 = splat4(16.f * b2[d]);

#pragma unroll
    for (int ks = 0; ks < 16; ++ks) {
        int h0 = ks * 32 + quad * 8;
        bf16x8 a2 = *(bf16x8*)(&hs[col][h0]);
        bf16x8 bw = *(const bf16x8*)(W2b + d * HH + h0);
        acc2 = __builtin_amdgcn_mfma_f32_16x16x32_bf16(a2, bw, acc2, 0, 0, 0);
    }

#pragma unroll
    for (int r = 0; r < 4; ++r) {
        int j = quad * 4 + r;
        out[(size_t)b * (AA * DD) + j * DD + d] = acc2[r];
    }
}

extern "C" void kernel_launch(void* const* d_in, const int* in_sizes, int n_in,
                              void* d_out, int out_size, void* d_ws, size_t ws_size,
                              hipStream_t stream)
{
    const float* x  = (const float*)d_in[0];  // [2048,16,128]
    const float* W1 = (const float*)d_in[1];  // [512,128]
    const float* b1 = (const float*)d_in[2];  // [512]
    const float* W2 = (const float*)d_in[3];  // [128,512]
    const float* b2 = (const float*)d_in[4];  // [128]
    float* out = (float*)d_out;

    bf16* wsb = (bf16*)d_ws;                  // 256 KB used
    convert_weights<<<128, 256, 0, stream>>>(W1, W2, wsb);

    const bf16* W1b = wsb;
    const bf16* W2b = wsb + (size_t)HH * DD;
    interact_kernel<<<BATCH, 512, 0, stream>>>(x, W1b, b1, W2b, b2, out);
}

// Round 8
// 164.921 us; speedup vs baseline: 1.4571x; 1.0037x over previous
//
#include <hip/hip_runtime.h>

// InternalInteraction: out[b,j,d] = sum_i [ relu((x_i*x_j)@W1^T + b1) @ W2^T + b2 ]
// Factored: hsum[b,j,h] = sum_i relu((x_i*x_j)@W1^T + b1); out = hsum@W2^T + 16*b2.
// B=2048, A=16, D=128, H=512. Storage fp32; MFMA in bf16.
//
// Round-11 structure (vs round-10):
//  - POST-MORTEM r10: (512,2) fixed the spill but halved residency to
//    8 waves/CU -> 87->105us. Kernel is occupancy-sensitive BELOW 16
//    waves/CU (r5: insensitive above). DPP value still unmeasured.
//  - FIX: 1024-thread blocks, 16 waves, each wave owns 32 h-cols (n=2).
//    Per-wave regs: w1f 32 + bias 8 + hsum 8 + srot 8 + v 8 + af 16 +
//    misc ~= 100 <= 128 -> DPP-Horner fits the (1024,4) 128-reg tier.
//    16 waves/CU = r8's residency, WITH the DPP rotation.
//    Per-CU LDS traffic identical to r8 (same af pattern x same wave count).
//  - GEMM2 runs on waves 0-7 (geometry unchanged); waves 8-15 retire
//    after the final barrier (short tail, zero complexity risk).
//  - DPP-HORNER (kept): srot = v_dlt + ror1(srot) for dlt=7..1, then
//    hsum += ror1(srot). Replaces 112 ds_bpermute/wave with mov_dpp.
//  - Symmetry cut (r8): 9 shift tiles, swapped-operand GEMM1 (C rows=h,
//    cols=j), unroll-1 loop, hs aliasing dead ps.

#define BATCH 2048
#define AA 16
#define DD 128
#define HH 512

typedef __bf16 bf16;
typedef bf16  bf16x2 __attribute__((ext_vector_type(2)));
typedef bf16  bf16x4 __attribute__((ext_vector_type(4)));
typedef bf16  bf16x8 __attribute__((ext_vector_type(8)));
typedef float f32x2  __attribute__((ext_vector_type(2)));
typedef float f32x4  __attribute__((ext_vector_type(4)));

__device__ inline f32x4 splat4(float v) { f32x4 r = {v, v, v, v}; return r; }

// rotate within each 16-lane row: lane j takes lane (j-1)&15 (DPP row_ror:1)
__device__ inline float ror1_f32(float v) {
    return __int_as_float(__builtin_amdgcn_mov_dpp(
        __float_as_int(v), 0x121, 0xF, 0xF, false));
}

// ---- prologue: fp32 -> bf16 weight conversion into d_ws ----
// ws layout: [0, 65536)  = W1b (512x128 row-major bf16)
//            [65536, ..) = W2b (128x512 row-major bf16)
__global__ __launch_bounds__(256, 1)
void convert_weights(const float* __restrict__ W1,
                     const float* __restrict__ W2,
                     bf16* __restrict__ wsb)
{
    int t = blockIdx.x * 256 + threadIdx.x;      // 0..32767, 4 elems each
    f32x4 v = (t < 16384) ? *(const f32x4*)(W1 + 4 * t)
                          : *(const f32x4*)(W2 + 4 * (t - 16384));
    bf16x4 o;
    o[0] = (bf16)v[0]; o[1] = (bf16)v[1]; o[2] = (bf16)v[2]; o[3] = (bf16)v[3];
    *(bf16x4*)(wsb + 4 * t) = o;
}

// One block per batch. 1024 threads = 16 waves; wave w owns H cols [w*32, w*32+32).
__global__ __launch_bounds__(1024, 4)
void interact_kernel(const float* __restrict__ x,    // [B, A, D] fp32
                     const bf16*  __restrict__ W1b,  // [H, D] bf16 (from ws)
                     const float* __restrict__ b1,   // [H]
                     const bf16*  __restrict__ W2b,  // [D, H] bf16 (from ws)
                     const float* __restrict__ b2,   // [D]
                     float* __restrict__ out)        // [B, A, D] fp32
{
    // xs: x_b in f32, row stride 136 (544 B)
    __shared__ float xs[16][136];                               // 8704 B
    // ps: 9 shift-tiles [dlt][j][136] bf16; tile dlt row j = x_{(j+dlt)&15}*x_j.
    //     row stride 272 B -> frag b128 reads uniform over 8 bank-slots.
    // hs: GEMM2 staging [16][520] bf16 (16640 B) -- ALIASES ps (dead by then).
    __shared__ __align__(16) unsigned char smem_raw[9 * 16 * 136 * 2];  // 39168 B
    bf16 (*ps)[16][136] = reinterpret_cast<bf16(*)[16][136]>(smem_raw);
    bf16 (*hs)[520]     = reinterpret_cast<bf16(*)[520]>(smem_raw);

    const int b    = blockIdx.x;
    const int tid  = threadIdx.x;
    const int wave = tid >> 6;    // 0..15
    const int lane = tid & 63;
    const int quad = lane >> 4;   // 0..3
    const int col  = lane & 15;   // 0..15

    // build-phase coordinates: wave w owns row jrow=w; lane owns 2 d-elems
    const int jrow = wave;              // 0..15
    const int dq   = lane * 2;          // 0..126

    // ---- stage x_b into LDS (f32); keep own 2-float slice in regs ----
    f32x2 xj;
    {
        const float* src = x + (size_t)b * (AA * DD) + jrow * DD + dq;
        xj = *(const f32x2*)src;
        *(f32x2*)(&xs[jrow][dq]) = xj;
    }

    // ---- W1 fragments, register-resident (2n x 4kk x 16B = 32 regs) ----
    // Used as MFMA arg0 (A-operand): lane holds W1b[h = n*16+col][k-slice].
    bf16x8 w1f[2][4];
    f32x4  bias4[2];   // C-seed: b1[h0 + quad*4 + r] per reg r (C rows = h)
#pragma unroll
    for (int n = 0; n < 2; ++n) {
        int h    = wave * 32 + n * 16 + col;
        bias4[n] = *(const f32x4*)(b1 + wave * 32 + n * 16 + quad * 4);
#pragma unroll
        for (int kk = 0; kk < 4; ++kk)
            w1f[n][kk] = *(const bf16x8*)(W1b + h * DD + kk * 32 + quad * 8);
    }

    f32x4 hsum[2];   // aligned accumulator
    f32x4 srot[2];   // Horner accumulator for the rotated sum
#pragma unroll
    for (int n = 0; n < 2; ++n) { hsum[n] = splat4(0.f); srot[n] = splat4(0.f); }

    __syncthreads();   // xs complete

    // ---- build 9 shift tiles: ps[dlt][j][d] = bf16(x_{(j+dlt)&15}[d]*x_j[d]) ----
#pragma unroll
    for (int dlt = 0; dlt < 9; ++dlt) {
        f32x2 xi = *(f32x2*)(&xs[(jrow + dlt) & 15][dq]);
        bf16x2 pr;
        pr[0] = (bf16)(xj[0] * xi[0]);
        pr[1] = (bf16)(xj[1] * xi[1]);
        *(bf16x2*)(&ps[dlt][jrow][dq]) = pr;
    }
    __syncthreads();   // all tiles ready; no barriers until GEMM2 staging

    // ---- GEMM1 over 9 shift tiles (SWAPPED operands: C rows=h, cols=j) ----
    // v_dlt = relu(W1 @ pair_dlt + b1); lane(q,c) holds v[h=base+n*16+q*4+r][j=c].
    // hsum[j]  = sum_{dlt=0..8} v_dlt[j]                     (aligned adds)
    // rotated  = sum_{dlt=1..7} v_dlt[(j-dlt)&15]            (tiles 16-dlt)
    // Horner over DESCENDING dlt: srot = v_dlt + ror1(srot) for dlt=7..1;
    // then rotated = ror1(srot). ror1 is DPP row_ror:1 -- pure VALU.
#pragma unroll 1
    for (int dlt = 8; dlt >= 0; --dlt) {
        bf16x8 af[4];
#pragma unroll
        for (int kk = 0; kk < 4; ++kk)
            af[kk] = *(bf16x8*)(&ps[dlt][col][kk * 32 + quad * 8]);

        f32x4 v[2];
#pragma unroll
        for (int n = 0; n < 2; ++n)
            v[n] = __builtin_amdgcn_mfma_f32_16x16x32_bf16(
                w1f[n][0], af[0], bias4[n], 0, 0, 0);
#pragma unroll
        for (int kk = 1; kk < 4; ++kk)
#pragma unroll
            for (int n = 0; n < 2; ++n)
                v[n] = __builtin_amdgcn_mfma_f32_16x16x32_bf16(
                    w1f[n][kk], af[kk], v[n], 0, 0, 0);

        // relu + aligned add
#pragma unroll
        for (int n = 0; n < 2; ++n)
#pragma unroll
            for (int r = 0; r < 4; ++r) {
                v[n][r] = fmaxf(v[n][r], 0.f);
                hsum[n][r] += v[n][r];
            }

        // Horner step for the rotated sum (uniform branch, unroll-1 loop)
        if (dlt >= 1 && dlt <= 7) {
#pragma unroll
            for (int n = 0; n < 2; ++n)
#pragma unroll
                for (int r = 0; r < 4; ++r)
                    srot[n][r] = v[n][r] + ror1_f32(srot[n][r]);
        }
    }

    // close the Horner chain: hsum += R(srot)
#pragma unroll
    for (int n = 0; n < 2; ++n)
#pragma unroll
        for (int r = 0; r < 4; ++r)
            hsum[n][r] += ror1_f32(srot[n][r]);

    __syncthreads();   // all ps reads done before hs overwrites the region

    // ---- hsum -> LDS (bf16) for GEMM2 A-operand re-layout ----
    // Transposed C layout: lane(q,c) holds hsum[j=c][h = w*32+n*16+q*4+r]
    // -> contiguous in h: one bf16x4 store per n.
#pragma unroll
    for (int n = 0; n < 2; ++n) {
        bf16x4 o;
#pragma unroll
        for (int r = 0; r < 4; ++r) o[r] = (bf16)hsum[n][r];
        *(bf16x4*)(&hs[col][wave * 32 + n * 16 + quad * 4]) = o;
    }

    __syncthreads();

    // ---- GEMM2 on waves 0-7: out[j,d] = hsum[j,:] @ W2^T + 16*b2 ----
    // M=16 (j), N=16 per wave (d = wave*16 + col), K=512 (h). W2b is [D,H].
    if (wave < 8) {
        const int d = wave * 16 + col;
        f32x4 acc2 = splat4(16.f * b2[d]);

#pragma unroll
        for (int ks = 0; ks < 16; ++ks) {
            int h0 = ks * 32 + quad * 8;
            bf16x8 a2 = *(bf16x8*)(&hs[col][h0]);
            bf16x8 bw = *(const bf16x8*)(W2b + d * HH + h0);
            acc2 = __builtin_amdgcn_mfma_f32_16x16x32_bf16(a2, bw, acc2, 0, 0, 0);
        }

#pragma unroll
        for (int r = 0; r < 4; ++r) {
            int j = quad * 4 + r;
            out[(size_t)b * (AA * DD) + j * DD + d] = acc2[r];
        }
    }
}

extern "C" void kernel_launch(void* const* d_in, const int* in_sizes, int n_in,
                              void* d_out, int out_size, void* d_ws, size_t ws_size,
                              hipStream_t stream)
{
    const float* x  = (const float*)d_in[0];  // [2048,16,128]
    const float* W1 = (const float*)d_in[1];  // [512,128]
    const float* b1 = (const float*)d_in[2];  // [512]
    const float* W2 = (const float*)d_in[3];  // [128,512]
    const float* b2 = (const float*)d_in[4];  // [128]
    float* out = (float*)d_out;

    bf16* wsb = (bf16*)d_ws;                  // 256 KB used
    convert_weights<<<128, 256, 0, stream>>>(W1, W2, wsb);

    const bf16* W1b = wsb;
    const bf16* W2b = wsb + (size_t)HH * DD;
    interact_kernel<<<BATCH, 1024, 0, stream>>>(x, W1b, b1, W2b, b2, out);
}

// Round 9
// 161.684 us; speedup vs baseline: 1.4863x; 1.0200x over previous
//
#include <hip/hip_runtime.h>

// InternalInteraction: out[b,j,d] = sum_i [ relu((x_i*x_j)@W1^T + b1) @ W2^T + b2 ]
// Factored: hsum[b,j,h] = sum_i relu((x_i*x_j)@W1^T + b1); out = hsum@W2^T + 16*b2.
// B=2048, A=16, D=128, H=512. Storage fp32; MFMA in bf16.
//
// Round-12 structure (vs round-11):
//  - POST-MORTEM r11: af-fragment LDS reads are PER-WAVE and independent of
//    the per-wave h-tile width (each wave reads the full 16x128 tile slice).
//    16 waves of 32h doubled af traffic (bank conflicts 3.67M->6.03M) and
//    ate the DPP gain. The DPP-vs-bpermute A/B at equal traffic never ran.
//  - THIS ROUND = r8 EXACTLY (512 thr, 8 waves, 64 h/wave, (512,4),
//    2 blocks/CU, 36 af-b128/wave) with ONE change: the rotated add.
//    bpermute (LDS pipe, 112/wave) -> mov_dpp row_ror:dlt (VALU).
//    Horner's srot accumulator (r9's +16-reg spill trap) is avoided by a
//    UNIFORM SWITCH on dlt inside the unroll-1 loop: each case has a
//    compile-time DPP immediate. Zero extra registers vs r8.
//  - DPP semantics validated by r10/r11 passing: ctrl 0x120+N = lane j
//    receives lane (j-N)&15 within its 16-lane row = v[(j-dlt)&15].
//  - Symmetry cut (r8): 9 shift tiles; tiles dlt and 16-dlt are equal
//    row-rotated; hsum[j] = v_0[j] + v_8[j]
//                         + sum_{d=1..7} (v_d[j] + v_d[(j-d)&15]).
//    Swapped-operand GEMM1 (C rows=h, cols=j) makes the rotation pure-lane.

#define BATCH 2048
#define AA 16
#define DD 128
#define HH 512

typedef __bf16 bf16;
typedef bf16  bf16x4 __attribute__((ext_vector_type(4)));
typedef bf16  bf16x8 __attribute__((ext_vector_type(8)));
typedef float f32x4  __attribute__((ext_vector_type(4)));

__device__ inline f32x4 splat4(float v) { f32x4 r = {v, v, v, v}; return r; }

// hsum[j] += v[(j-N)&15] within each 16-lane row, compile-time N (DPP row_ror:N)
template <int N>
__device__ __forceinline__ void rot_add(f32x4 (&hsum)[4], const f32x4 (&v)[4]) {
#pragma unroll
    for (int n = 0; n < 4; ++n)
#pragma unroll
        for (int r = 0; r < 4; ++r)
            hsum[n][r] += __int_as_float(__builtin_amdgcn_mov_dpp(
                __float_as_int(v[n][r]), 0x120 + N, 0xF, 0xF, false));
}

// ---- prologue: fp32 -> bf16 weight conversion into d_ws ----
// ws layout: [0, 65536)  = W1b (512x128 row-major bf16)
//            [65536, ..) = W2b (128x512 row-major bf16)
__global__ __launch_bounds__(256, 1)
void convert_weights(const float* __restrict__ W1,
                     const float* __restrict__ W2,
                     bf16* __restrict__ wsb)
{
    int t = blockIdx.x * 256 + threadIdx.x;      // 0..32767, 4 elems each
    f32x4 v = (t < 16384) ? *(const f32x4*)(W1 + 4 * t)
                          : *(const f32x4*)(W2 + 4 * (t - 16384));
    bf16x4 o;
    o[0] = (bf16)v[0]; o[1] = (bf16)v[1]; o[2] = (bf16)v[2]; o[3] = (bf16)v[3];
    *(bf16x4*)(wsb + 4 * t) = o;
}

// One block per batch. 512 threads = 8 waves; wave w owns H cols [w*64, w*64+64).
__global__ __launch_bounds__(512, 4)
void interact_kernel(const float* __restrict__ x,    // [B, A, D] fp32
                     const bf16*  __restrict__ W1b,  // [H, D] bf16 (from ws)
                     const float* __restrict__ b1,   // [H]
                     const bf16*  __restrict__ W2b,  // [D, H] bf16 (from ws)
                     const float* __restrict__ b2,   // [D]
                     float* __restrict__ out)        // [B, A, D] fp32
{
    // xs: x_b in f32, row stride 136 (544 B)
    __shared__ float xs[16][136];                               // 8704 B
    // ps: 9 shift-tiles [dlt][j][136] bf16; tile dlt row j = x_{(j+dlt)&15}*x_j.
    //     row stride 272 B -> frag b128 reads uniform over 8 bank-slots.
    // hs: GEMM2 staging [16][520] bf16 (16640 B) -- ALIASES ps (dead by then).
    __shared__ __align__(16) unsigned char smem_raw[9 * 16 * 136 * 2];  // 39168 B
    bf16 (*ps)[16][136] = reinterpret_cast<bf16(*)[16][136]>(smem_raw);
    bf16 (*hs)[520]     = reinterpret_cast<bf16(*)[520]>(smem_raw);

    const int b    = blockIdx.x;
    const int tid  = threadIdx.x;
    const int wave = tid >> 6;    // 0..7
    const int lane = tid & 63;
    const int quad = lane >> 4;   // 0..3
    const int col  = lane & 15;   // 0..15

    // build-phase coordinates: thread owns (jrow, dq..dq+4)
    const int jrow = tid >> 5;          // 0..15
    const int dq   = (tid & 31) * 4;    // 0..124

    // ---- stage x_b into LDS (f32); keep own 4-float slice in regs ----
    f32x4 xj;
    {
        const float* src = x + (size_t)b * (AA * DD) + jrow * DD + dq;
        xj = *(const f32x4*)src;
        *(f32x4*)(&xs[jrow][dq]) = xj;
    }

    // ---- W1 fragments, register-resident (4n x 4kk x 16B = 64 regs) ----
    // Used as MFMA arg0 (A-operand): lane holds W1b[h = n*16+col][k-slice].
    bf16x8 w1f[4][4];
    f32x4  bias4[4];   // C-seed: b1[h0 + quad*4 + r] per reg r (C rows = h)
#pragma unroll
    for (int n = 0; n < 4; ++n) {
        int h    = wave * 64 + n * 16 + col;
        bias4[n] = *(const f32x4*)(b1 + wave * 64 + n * 16 + quad * 4);
#pragma unroll
        for (int kk = 0; kk < 4; ++kk)
            w1f[n][kk] = *(const bf16x8*)(W1b + h * DD + kk * 32 + quad * 8);
    }

    f32x4 hsum[4];
#pragma unroll
    for (int n = 0; n < 4; ++n) hsum[n] = splat4(0.f);

    __syncthreads();   // xs complete

    // ---- build 9 shift tiles: ps[dlt][j][d] = bf16(x_{(j+dlt)&15}[d]*x_j[d]) ----
#pragma unroll
    for (int dlt = 0; dlt < 9; ++dlt) {
        f32x4 xi = *(f32x4*)(&xs[(jrow + dlt) & 15][dq]);
        bf16x4 pr;
#pragma unroll
        for (int e = 0; e < 4; ++e) pr[e] = (bf16)(xj[e] * xi[e]);
        *(bf16x4*)(&ps[dlt][jrow][dq]) = pr;
    }
    __syncthreads();   // all tiles ready; no barriers until GEMM2 staging

    // ---- GEMM1 over 9 shift tiles (SWAPPED operands: C rows=h, cols=j) ----
    // v_dlt = relu(W1 @ pair_dlt + b1); lane(q,c) holds v[h=base+n*16+q*4+r][j=c].
    // hsum[j] += v_dlt[j] always; for dlt=1..7 also += v_dlt[(j-dlt)&15]
    // via DPP row_ror:dlt (compile-time imm per switch case, pure VALU).
#pragma unroll 1
    for (int dlt = 0; dlt < 9; ++dlt) {
        bf16x8 af[4];
#pragma unroll
        for (int kk = 0; kk < 4; ++kk)
            af[kk] = *(bf16x8*)(&ps[dlt][col][kk * 32 + quad * 8]);

        f32x4 v[4];
#pragma unroll
        for (int n = 0; n < 4; ++n)
            v[n] = __builtin_amdgcn_mfma_f32_16x16x32_bf16(
                w1f[n][0], af[0], bias4[n], 0, 0, 0);
#pragma unroll
        for (int kk = 1; kk < 4; ++kk)
#pragma unroll
            for (int n = 0; n < 4; ++n)
                v[n] = __builtin_amdgcn_mfma_f32_16x16x32_bf16(
                    w1f[n][kk], af[kk], v[n], 0, 0, 0);

        // relu + aligned add
#pragma unroll
        for (int n = 0; n < 4; ++n)
#pragma unroll
            for (int r = 0; r < 4; ++r) {
                v[n][r] = fmaxf(v[n][r], 0.f);
                hsum[n][r] += v[n][r];
            }

        // rotated add (tile 16-dlt), uniform branch, compile-time DPP imm
        switch (dlt) {
            case 1: rot_add<1>(hsum, v); break;
            case 2: rot_add<2>(hsum, v); break;
            case 3: rot_add<3>(hsum, v); break;
            case 4: rot_add<4>(hsum, v); break;
            case 5: rot_add<5>(hsum, v); break;
            case 6: rot_add<6>(hsum, v); break;
            case 7: rot_add<7>(hsum, v); break;
            default: break;   // dlt = 0, 8: single add only
        }
    }

    __syncthreads();   // all ps reads done before hs overwrites the region

    // ---- hsum -> LDS (bf16) for GEMM2 A-operand re-layout ----
    // Transposed C layout: lane(q,c) holds hsum[j=c][h = w*64+n*16+q*4+r]
    // -> contiguous in h: one bf16x4 store per n.
#pragma unroll
    for (int n = 0; n < 4; ++n) {
        bf16x4 o;
#pragma unroll
        for (int r = 0; r < 4; ++r) o[r] = (bf16)hsum[n][r];
        *(bf16x4*)(&hs[col][wave * 64 + n * 16 + quad * 4]) = o;
    }

    __syncthreads();

    // ---- GEMM2: out[j,d] = hsum[j,:] @ W2^T + 16*b2 ----
    // M=16 (j), N=16 per wave (d = wave*16 + col), K=512 (h). W2b is [D,H].
    const int d = wave * 16 + col;
    f32x4 acc2 = splat4(16.f * b2[d]);

#pragma unroll
    for (int ks = 0; ks < 16; ++ks) {
        int h0 = ks * 32 + quad * 8;
        bf16x8 a2 = *(bf16x8*)(&hs[col][h0]);
        bf16x8 bw = *(const bf16x8*)(W2b + d * HH + h0);
        acc2 = __builtin_amdgcn_mfma_f32_16x16x32_bf16(a2, bw, acc2, 0, 0, 0);
    }

#pragma unroll
    for (int r = 0; r < 4; ++r) {
        int j = quad * 4 + r;
        out[(size_t)b * (AA * DD) + j * DD + d] = acc2[r];
    }
}

extern "C" void kernel_launch(void* const* d_in, const int* in_sizes, int n_in,
                              void* d_out, int out_size, void* d_ws, size_t ws_size,
                              hipStream_t stream)
{
    const float* x  = (const float*)d_in[0];  // [2048,16,128]
    const float* W1 = (const float*)d_in[1];  // [512,128]
    const float* b1 = (const float*)d_in[2];  // [512]
    const float* W2 = (const float*)d_in[3];  // [128,512]
    const float* b2 = (const float*)d_in[4];  // [128]
    float* out = (float*)d_out;

    bf16* wsb = (bf16*)d_ws;                  // 256 KB used
    convert_weights<<<128, 256, 0, stream>>>(W1, W2, wsb);

    const bf16* W1b = wsb;
    const bf16* W2b = wsb + (size_t)HH * DD;
    interact_kernel<<<BATCH, 512, 0, stream>>>(x, W1b, b1, W2b, b2, out);
}